// Round 6
// baseline (333.602 us; speedup 1.0000x reference)
//
#include <hip/hip_runtime.h>
#include <hip/hip_bf16.h>
#include <stdint.h>

// Problem constants
#define M_TOK   16384        // 8 * 2048 tokens
#define EMBED   1024
#define FFN     4096
#define NQ      10

typedef __attribute__((ext_vector_type(8))) short  bf16x8;
typedef __attribute__((ext_vector_type(4))) float  f32x4;
typedef __attribute__((ext_vector_type(8))) unsigned short u16x8;

static __device__ __forceinline__ unsigned short f2bf(float f) {
    union { float f; unsigned u; } v; v.f = f;
    unsigned r = v.u + 0x7FFF + ((v.u >> 16) & 1);   // round-to-nearest-even
    return (unsigned short)(r >> 16);
}

// ---------------------------------------------------------------------------
// Kernel 1: h[t][f] = relu( sum_i cos(x[t][i]) * cos(ry[i]) * w1[f][i] ) -> bf16
// (R5 version — measured gap analysis says this is not on the critical path)
// ---------------------------------------------------------------------------
__global__ __launch_bounds__(256) void compute_h(
    const float* __restrict__ x, const float* __restrict__ ry,
    const float* __restrict__ w1, unsigned short* __restrict__ h)
{
    __shared__ float cq[32 * 16];    // 2 KB, stride 16 for alignment
    __shared__ float cry[NQ];

    const int tid = threadIdx.x;
    const int t0  = blockIdx.x * 32;
    const int fb  = blockIdx.y * 2048 + tid * 8;   // this thread's 8 f's

    if (tid < NQ) cry[tid] = cosf(ry[tid]);
    for (int idx = tid; idx < 32 * NQ; idx += 256) {
        int t = idx / NQ;
        int i = idx - t * NQ;
        cq[t * 16 + i] = cosf(x[(size_t)(t0 + t) * EMBED + i]);
    }
    __syncthreads();

    float wf[8][NQ];
#pragma unroll
    for (int fi = 0; fi < 8; ++fi)
#pragma unroll
        for (int i = 0; i < NQ; ++i)
            wf[fi][i] = w1[(fb + fi) * NQ + i] * cry[i];

    for (int t = 0; t < 32; ++t) {
        const float4 c0 = *(const float4*)&cq[t * 16 + 0];
        const float4 c1 = *(const float4*)&cq[t * 16 + 4];
        const float2 c2 = *(const float2*)&cq[t * 16 + 8];
        u16x8 v;
#pragma unroll
        for (int fi = 0; fi < 8; ++fi) {
            float s = c0.x * wf[fi][0] + c0.y * wf[fi][1] + c0.z * wf[fi][2]
                    + c0.w * wf[fi][3] + c1.x * wf[fi][4] + c1.y * wf[fi][5]
                    + c1.z * wf[fi][6] + c1.w * wf[fi][7] + c2.x * wf[fi][8]
                    + c2.y * wf[fi][9];
            v[fi] = f2bf(fmaxf(s, 0.f));
        }
        *(u16x8*)(h + (size_t)(t0 + t) * FFN + fb) = v;
    }
}

// ---------------------------------------------------------------------------
// Kernel 2: w2 fp32 -> bf16.
// ---------------------------------------------------------------------------
__global__ __launch_bounds__(256) void conv_w2(
    const float* __restrict__ w2, unsigned short* __restrict__ o)
{
    const int idx = (blockIdx.x * 256 + threadIdx.x) * 8;
    float4 a = *(const float4*)(w2 + idx);
    float4 b = *(const float4*)(w2 + idx + 4);
    u16x8 v;
    v[0] = f2bf(a.x); v[1] = f2bf(a.y); v[2] = f2bf(a.z); v[3] = f2bf(a.w);
    v[4] = f2bf(b.x); v[5] = f2bf(b.y); v[6] = f2bf(b.z); v[7] = f2bf(b.w);
    *(u16x8*)(o + idx) = v;
}

// ---------------------------------------------------------------------------
// Kernel 3: C = A * B^T, producer-consumer wave specialization.
// 320 threads: waves 0-3 = consumers (2x2 grid of 64x64 sub-tiles, 4x4 MFMA
// 16x16x32 each, identical math + XOR bank swizzle to R5), wave 4 = producer.
// 2-stage LDS ring (2 x 32 KB = 64 KB). Per iter the producer stages tile
// k+1 into stage (k+1)&1 (32 global_load_lds dwordx4) and is the ONLY wave
// whose __syncthreads-drain (vmcnt(0)) has outstanding loads -- its stall
// overlaps the consumers' MFMA on stage k&1. Both paths: NKI+1 barriers.
//
// LDS row = 128 B = 8 chunks. Staging lane -> (row lane>>3, chunk
// (lane&7)^(lane>>3)); image LDS[r][c] = global[r][c^(r&7)]; fragment read
// (s*4+cc)^(rr&7) round-trips. 2-way bank aliasing = free (m136).
// ---------------------------------------------------------------------------
#define GK 4096
#define GN 1024
#define BK 64
#define NKI (GK / BK)   // 64

#define GL2LDS(g, l) \
    __builtin_amdgcn_global_load_lds( \
        (const __attribute__((address_space(1))) void*)(g), \
        (__attribute__((address_space(3))) void*)(l), 16, 0, 0)

__global__ __launch_bounds__(320) void gemm_bt(
    const unsigned short* __restrict__ A,
    const unsigned short* __restrict__ B,
    float* __restrict__ C)
{
    __shared__ unsigned short At[2][128 * BK];   // 2 x 16 KB
    __shared__ unsigned short Bt[2][128 * BK];   // 2 x 16 KB

    const int tid  = threadIdx.x;
    const int wv   = tid >> 6;
    const int lane = tid & 63;

    // XCD-aware decode (same as R5)
    const int bid   = blockIdx.x;
    const int group = bid >> 6;            // 0..15
    const int g     = bid & 63;
    const int m_blk = group * 8 + (g & 7); // 0..127
    const int n_blk = g >> 3;              // 0..7
    const int m0 = m_blk * 128;
    const int n0 = n_blk * 128;

    if (wv == 4) {
        // ---------------- producer wave ----------------
        const int srow  = lane >> 3;                   // 0..7
        const int scolb = ((lane & 7) ^ srow) * 16;    // byte offset in row

        const char* Abase = (const char*)A + (size_t)(m0 + srow) * (GK * 2) + scolb;
        const char* Bbase = (const char*)B + (size_t)(n0 + srow) * (GK * 2) + scolb;

        // prologue: stage 0 <- tile k=0
#pragma unroll
        for (int rg = 0; rg < 16; ++rg) {
            GL2LDS(Abase + (size_t)rg * 8 * (GK * 2), (char*)At[0] + rg * 1024);
            GL2LDS(Bbase + (size_t)rg * 8 * (GK * 2), (char*)Bt[0] + rg * 1024);
        }
        __syncthreads();                       // barrier #0 (vmcnt(0) drain: producer only)

        for (int k = 0; k < NKI; ++k) {
            if (k + 1 < NKI) {
                const int s  = (k + 1) & 1;
                const size_t koff = (size_t)(k + 1) * BK * 2;   // bytes
#pragma unroll
                for (int rg = 0; rg < 16; ++rg) {
                    GL2LDS(Abase + (size_t)rg * 8 * (GK * 2) + koff,
                           (char*)At[s] + rg * 1024);
                    GL2LDS(Bbase + (size_t)rg * 8 * (GK * 2) + koff,
                           (char*)Bt[s] + rg * 1024);
                }
            }
            __syncthreads();                   // barriers #1..#NKI
        }
        // producer exits; consumers' epilogue has no barriers
    } else {
        // ---------------- consumer waves ----------------
        const int wr = (wv & 1) * 64;      // wave row offset
        const int wc = (wv >> 1) * 64;     // wave col offset

        f32x4 acc[4][4] = {};

        const int rr = lane & 15;
        const int cc = lane >> 4;
        const int f0off = rr * 128 + (((0 * 4 + cc) ^ (rr & 7)) * 16);
        const int f1off = rr * 128 + (((1 * 4 + cc) ^ (rr & 7)) * 16);

        __syncthreads();                       // barrier #0: stage 0 ready

        for (int k = 0; k < NKI; ++k) {
            const int s = k & 1;
#pragma unroll
            for (int st = 0; st < 2; ++st) {
                const int foff = st ? f1off : f0off;
                bf16x8 af[4], bf[4];
#pragma unroll
                for (int i = 0; i < 4; ++i) {
                    af[i] = *(const bf16x8*)((const char*)At[s] + (wr + i * 16) * 128 + foff);
                    bf[i] = *(const bf16x8*)((const char*)Bt[s] + (wc + i * 16) * 128 + foff);
                }
#pragma unroll
                for (int i = 0; i < 4; ++i)
#pragma unroll
                    for (int j = 0; j < 4; ++j)
                        acc[i][j] = __builtin_amdgcn_mfma_f32_16x16x32_bf16(
                            af[i], bf[j], acc[i][j], 0, 0, 0);
            }
            __syncthreads();                   // barriers #1..#NKI
        }

        // epilogue: C/D layout col = lane&15, row = (lane>>4)*4 + reg
        const int cn    = lane & 15;
        const int rbase = (lane >> 4) * 4;
#pragma unroll
        for (int i = 0; i < 4; ++i)
#pragma unroll
            for (int j = 0; j < 4; ++j)
#pragma unroll
                for (int r = 0; r < 4; ++r) {
                    const int m = m0 + wr + i * 16 + rbase + r;
                    const int n = n0 + wc + j * 16 + cn;
                    C[(size_t)m * GN + n] = acc[i][j][r];
                }
    }
}

// ---------------------------------------------------------------------------
extern "C" void kernel_launch(void* const* d_in, const int* in_sizes, int n_in,
                              void* d_out, int out_size, void* d_ws, size_t ws_size,
                              hipStream_t stream) {
    const float* x  = (const float*)d_in[0];
    const float* ry = (const float*)d_in[1];
    const float* w1 = (const float*)d_in[2];
    const float* w2 = (const float*)d_in[3];
    float* out = (float*)d_out;

    unsigned short* h   = (unsigned short*)d_ws;                       // 128 MiB
    unsigned short* w2b = (unsigned short*)((char*)d_ws +
                           (size_t)M_TOK * FFN * sizeof(unsigned short));

    compute_h<<<dim3(512, 2), 256, 0, stream>>>(x, ry, w1, h);
    conv_w2<<<dim3((EMBED * FFN) / (256 * 8)), 256, 0, stream>>>(w2, w2b);
    gemm_bt<<<dim3(1024), 320, 0, stream>>>(h, w2b, out);
}